// Round 8
// baseline (402.921 us; speedup 1.0000x reference)
//
#include <hip/hip_runtime.h>
#include <math.h>

#define KCLS  50000
#define KP    50048   // KCLS padded to multiple of 128 for the GEMM class dim
#define DIM   128
#define BATCH 1024
#define MAXD  16

#define NBLK_N   391              // KP/128 col-blocks in the GEMM
#define NBP      (NBLK_N * 2)     // 782 partial (m,s) pairs per row
#define XB_BLOCKS 128             // x-conversion blocks (folded into dispatch 0)

typedef __attribute__((ext_vector_type(8))) short short8;
typedef __attribute__((ext_vector_type(4))) float floatx4;

// round-to-nearest-even float -> bf16 bits (inputs are finite)
__device__ __forceinline__ unsigned short f2bf(float f) {
    unsigned u = __float_as_uint(f);
    u += 0x7fffu + ((u >> 16) & 1u);
    return (unsigned short)(u >> 16);
}

// ---------------------------------------------------------------------------
// Mixed-role kernel: software pipeline of aw against gemm ACROSS dispatches.
// Dispatch k runs gemm on col-block chunk k-1 (whose awb rows were written by
// dispatch k-1 — stream order guarantees visibility) co-scheduled with aw on
// chunk k. aw's gather-latency + L3-read work hides under gemm's MFMA +
// streaming-write work (disjoint pipes). Roles are whole-block:
//   bid < ngemm                      : gemm block (by = gemm_cb0 + bid/8)
//   ngemm <= bid < ngemm+aw_nblk     : aw block (8 classes, branchless gather)
//   else                             : x fp32->bf16 conversion (dispatch 0)
// Kernel bodies are the round-5/7-verified ones; only the id decode changed.
template<bool PART>
__global__ __launch_bounds__(256) void fused_kernel(
    const float* __restrict__ weights, const int* __restrict__ path_idx,
    const int* __restrict__ path_len, float* __restrict__ aw,
    unsigned short* __restrict__ awb,
    const float* __restrict__ x, unsigned short* __restrict__ xb,
    float* __restrict__ logits, float2* __restrict__ part,
    float* __restrict__ loss,
    int gemm_cb0, int ngemm, int aw_cls0, int aw_nblk)
{
    int bid = blockIdx.x;
    int t = threadIdx.x;

    if (bid < ngemm) {
        // ---------------- GEMM block: logits = Xb · Wb^T (swapped MFMA) ----
        // A = W-tile, B = X-tile -> each lane holds 4 consecutive classes of
        // one batch row -> plain floatx4 stores (merge to full lines in L2;
        // NT stores cost 1.84x WRITE_SIZE, round 4).
        int bx = bid & 7;                        // batch block (fastest)
        int by = gemm_cb0 + (bid >> 3);          // global col-block
        int wave = t >> 6, lane = t & 63;
        int r = lane & 15, quad = lane >> 4;
        int m0 = bx * 128 + (wave >> 1) * 64;    // batch rows
        int n0 = by * 128 + (wave & 1) * 64;     // class cols

        const unsigned short* wp = awb + (size_t)(n0 + r) * DIM + quad * 8;
        const unsigned short* xp = xb  + (size_t)(m0 + r) * DIM + quad * 8;

        floatx4 acc[4][4];   // [class-tile i][batch-tile j]
        #pragma unroll
        for (int i = 0; i < 4; ++i)
            #pragma unroll
            for (int j = 0; j < 4; ++j)
                acc[i][j] = (floatx4){0.f, 0.f, 0.f, 0.f};

        #pragma unroll
        for (int kk = 0; kk < 4; ++kk) {
            short8 a[4], b[4];
            #pragma unroll
            for (int i = 0; i < 4; ++i)
                a[i] = *(const short8*)(wp + (size_t)(i * 16) * DIM + kk * 32);
            #pragma unroll
            for (int j = 0; j < 4; ++j)
                b[j] = *(const short8*)(xp + (size_t)(j * 16) * DIM + kk * 32);
            #pragma unroll
            for (int i = 0; i < 4; ++i)
                #pragma unroll
                for (int j = 0; j < 4; ++j)
                    acc[i][j] = __builtin_amdgcn_mfma_f32_16x16x32_bf16(
                        a[i], b[j], acc[i][j], 0, 0, 0);
        }

        #pragma unroll
        for (int j = 0; j < 4; ++j) {
            int mrow = m0 + j * 16 + r;
            float* rowp = logits + (size_t)mrow * KCLS;

            #pragma unroll
            for (int i = 0; i < 4; ++i) {
                int nb = n0 + i * 16 + quad * 4;
                if (nb < KCLS)                    // KCLS%4==0: all-valid or pad
                    *(floatx4*)(rowp + nb) = acc[i][j];
            }

            if constexpr (PART) {
                // wave-wide (64-class) max+sumexp for this batch row;
                // i==0 always valid (worst pad block starts at 49984).
                float mx = -INFINITY;
                #pragma unroll
                for (int i = 0; i < 4; ++i) {
                    bool ok = (n0 + i * 16 + quad * 4) < KCLS;
                    #pragma unroll
                    for (int reg = 0; reg < 4; ++reg) {
                        float v = ok ? acc[i][j][reg] : -INFINITY;
                        mx = fmaxf(mx, v);
                    }
                }
                mx = fmaxf(mx, __shfl_xor(mx, 16));
                mx = fmaxf(mx, __shfl_xor(mx, 32));
                float s = 0.f;
                #pragma unroll
                for (int i = 0; i < 4; ++i) {
                    bool ok = (n0 + i * 16 + quad * 4) < KCLS;
                    #pragma unroll
                    for (int reg = 0; reg < 4; ++reg) {
                        float v = ok ? acc[i][j][reg] : -INFINITY;
                        s += __expf(v - mx);      // exp(-inf)=0 for pad
                    }
                }
                s += __shfl_xor(s, 16);
                s += __shfl_xor(s, 32);
                if (quad == 0)
                    part[(size_t)mrow * NBP + by * 2 + (wave & 1)]
                        = make_float2(mx, s);
            }
        }
        return;
    }

    int abid = bid - ngemm;
    if (abid < aw_nblk) {
        // ---------------- AW block: added_weights gather (branchless) ------
        // 2 classes/wave (32 lanes x float4): 1KB per gather instruction.
        // p=0..7 issued unconditionally (padded indices are valid rows),
        // value-masked by p<plen; p=8..15 only if __any(plen>8).
        int wv_id = t >> 6;
        int lane  = t & 63;
        int half  = lane >> 5;
        int li    = lane & 31;
        int k     = aw_cls0 + abid * 8 + wv_id * 2 + half;   // < KP always
        int col   = li * 4;

        bool valid = k < KCLS;
        int kc = valid ? k : 0;

        float4 acc = {0.f, 0.f, 0.f, 0.f};
        int plen = 0;
        if (valid) {
            acc  = *(const float4*)(weights + (size_t)k * DIM + col);
            plen = path_len[k];
        }
        const int* pp = path_idx + (size_t)kc * MAXD;

        {   // batch 1: p = 0..7
            int idx[8];
            #pragma unroll
            for (int p = 0; p < 8; ++p) idx[p] = pp[p];
            float4 wvv[8];
            #pragma unroll
            for (int p = 0; p < 8; ++p)
                wvv[p] = *(const float4*)(weights + (size_t)idx[p] * DIM + col);
            #pragma unroll
            for (int p = 0; p < 8; ++p) {
                float m = (p < plen) ? 1.f : 0.f;
                acc.x += m * wvv[p].x; acc.y += m * wvv[p].y;
                acc.z += m * wvv[p].z; acc.w += m * wvv[p].w;
            }
        }
        if (__any(plen > 8)) {   // batch 2: p = 8..15 (wave-uniform skip)
            int idx[8];
            #pragma unroll
            for (int p = 0; p < 8; ++p) idx[p] = pp[8 + p];
            float4 wvv[8];
            #pragma unroll
            for (int p = 0; p < 8; ++p)
                wvv[p] = *(const float4*)(weights + (size_t)idx[p] * DIM + col);
            #pragma unroll
            for (int p = 0; p < 8; ++p) {
                float m = (8 + p < plen) ? 1.f : 0.f;
                acc.x += m * wvv[p].x; acc.y += m * wvv[p].y;
                acc.z += m * wvv[p].z; acc.w += m * wvv[p].w;
            }
        }

        if (valid)
            *(float4*)(aw + (size_t)k * DIM + col) = acc;   // fp32 output
        ushort4 hv = { f2bf(acc.x), f2bf(acc.y), f2bf(acc.z), f2bf(acc.w) };
        *(ushort4*)(awb + (size_t)k * DIM + col) = hv;      // pad rows -> 0
        return;
    }

    // ---------------- XB block: x fp32->bf16 (dispatch 0 only) -------------
    int xi = abid - aw_nblk;
    if (xi == 0 && t == 0) *loss = 0.f;       // replaces memset dispatch
    int i = (xi * 256 + t) * 4;
    float4 v = *(const float4*)(x + i);
    ushort4 hv = { f2bf(v.x), f2bf(v.y), f2bf(v.z), f2bf(v.w) };
    *(ushort4*)(xb + i) = hv;
}

// ---------------------------------------------------------------------------
// Reduce NBP=782 (m,s) partials per row -> lse -> loss. One wave per row.
__global__ __launch_bounds__(256) void lsereduce_kernel(
    const float2* __restrict__ part, const float* __restrict__ logits,
    const int* __restrict__ y, float* __restrict__ loss)
{
    int b = blockIdx.x * 4 + (threadIdx.x >> 6);
    int lane = threadIdx.x & 63;
    const float2* pr = part + (size_t)b * NBP;

    float m = -INFINITY, s = 0.f;
    for (int i = lane; i < NBP; i += 64) {
        float2 pv = pr[i];
        if (pv.x > m) {
            s = s * __expf(m - pv.x) + pv.y;
            m = pv.x;
        } else {
            s += pv.y * __expf(pv.x - m);
        }
    }
    #pragma unroll
    for (int off = 32; off; off >>= 1) {
        float m2 = __shfl_xor(m, off);
        float s2 = __shfl_xor(s, off);
        float M = fmaxf(m, m2);
        s = s * __expf(m - M) + s2 * __expf(m2 - M);
        m = M;
    }
    if (lane == 0) {
        float lse = m + __logf(s);
        float ly = logits[(size_t)b * KCLS + y[b]];
        atomicAdd(loss, (lse - ly) * (1.0f / BATCH));
    }
}

// ---------------------------------------------------------------------------
// Fallback (workspace too small for partials): per-row logsumexp over logits.
__global__ __launch_bounds__(256) void lse_kernel(
    const float* __restrict__ logits, const int* __restrict__ y,
    float* __restrict__ loss)
{
    int b = blockIdx.x;
    const float* row = logits + (size_t)b * KCLS;
    float m = -INFINITY, s = 0.f;

    auto upd = [&](float v) {
        if (v <= m) {
            s += __expf(v - m);
        } else {
            s = s * __expf(m - v) + 1.f;
            m = v;
        }
    };

    if (threadIdx.x < 3) upd(row[threadIdx.x]);
    const float4* rv = (const float4*)(row + 3);
    for (int i = threadIdx.x; i < 12499; i += 256) {
        float4 v = rv[i];
        upd(v.x); upd(v.y); upd(v.z); upd(v.w);
    }
    if (threadIdx.x == 3) upd(row[49999]);

    #pragma unroll
    for (int off = 32; off > 0; off >>= 1) {
        float m2 = __shfl_down(m, off);
        float s2 = __shfl_down(s, off);
        float M = fmaxf(m, m2);
        s = s * __expf(m - M) + s2 * __expf(m2 - M);
        m = M;
    }
    __shared__ float sm[4], ss[4];
    int w = threadIdx.x >> 6, l = threadIdx.x & 63;
    if (l == 0) { sm[w] = m; ss[w] = s; }
    __syncthreads();
    if (threadIdx.x == 0) {
        m = sm[0]; s = ss[0];
        #pragma unroll
        for (int i = 1; i < 4; ++i) {
            float M = fmaxf(m, sm[i]);
            s = s * __expf(m - M) + ss[i] * __expf(sm[i] - M);
            m = M;
        }
        float lse = m + __logf(s);
        float ly = row[y[b]];
        atomicAdd(loss, (lse - ly) * (1.0f / BATCH));
    }
}

// ---------------------------------------------------------------------------
extern "C" void kernel_launch(void* const* d_in, const int* in_sizes, int n_in,
                              void* d_out, int out_size, void* d_ws, size_t ws_size,
                              hipStream_t stream)
{
    const float* weights  = (const float*)d_in[0];   // [65536][128]
    const float* x        = (const float*)d_in[1];   // [1024][128]
    const int*   y        = (const int*)d_in[2];     // [1024]
    const int*   path_idx = (const int*)d_in[3];     // [50000][16]
    const int*   path_len = (const int*)d_in[4];     // [50000]

    float* out    = (float*)d_out;
    float* loss   = out;                                  // [1]
    float* logits = out + 1;                              // [1024][50000]
    float* aw     = out + 1 + (size_t)BATCH * KCLS;       // [50000][128]

    size_t awb_sz  = (size_t)KP * DIM * sizeof(unsigned short);     // 12.8 MB
    size_t xb_sz   = (size_t)BATCH * DIM * sizeof(unsigned short);  // 0.26 MB
    size_t part_sz = (size_t)BATCH * NBP * sizeof(float2);          // 6.4 MB

    unsigned short* awb = (unsigned short*)d_ws;
    unsigned short* xb  = awb + (size_t)KP * DIM;
    float2* part = (float2*)((char*)d_ws + awb_sz + xb_sz);
    bool fused = ws_size >= awb_sz + xb_sz + part_sz;

    if (fused) {
        // 4-chunk pipeline over the 391 col-blocks: {98, 98, 98, 97}.
        // Class-range starts: 0, 12544, 25088, 37632 (chunk_cb * 128).
        // aw blocks per chunk = chunk_cb * 16 (8 classes per block).
        // d0: aw(c0) + xconv + loss-zero
        fused_kernel<true><<<1568 + XB_BLOCKS, 256, 0, stream>>>(
            weights, path_idx, path_len, aw, awb, x, xb, logits, part, loss,
            0, 0, 0, 1568);
        // d1..d3: gemm(c{k-1}) co-scheduled with aw(c{k})
        fused_kernel<true><<<98 * 8 + 1568, 256, 0, stream>>>(
            weights, path_idx, path_len, aw, awb, x, xb, logits, part, loss,
            0, 98 * 8, 12544, 1568);
        fused_kernel<true><<<98 * 8 + 1568, 256, 0, stream>>>(
            weights, path_idx, path_len, aw, awb, x, xb, logits, part, loss,
            98, 98 * 8, 25088, 1568);
        fused_kernel<true><<<98 * 8 + 1552, 256, 0, stream>>>(
            weights, path_idx, path_len, aw, awb, x, xb, logits, part, loss,
            196, 98 * 8, 37632, 1552);
        // d4: gemm(c3) only
        fused_kernel<true><<<97 * 8, 256, 0, stream>>>(
            weights, path_idx, path_len, aw, awb, x, xb, logits, part, loss,
            294, 97 * 8, 0, 0);
        lsereduce_kernel<<<BATCH / 4, 256, 0, stream>>>(part, logits, y, loss);
    } else {
        // Un-pipelined fallback: aw all + xconv, then gemm all, then full LSE.
        fused_kernel<false><<<6256 + XB_BLOCKS, 256, 0, stream>>>(
            weights, path_idx, path_len, aw, awb, x, xb, logits, nullptr, loss,
            0, 0, 0, 6256);
        fused_kernel<false><<<NBLK_N * 8, 256, 0, stream>>>(
            weights, path_idx, path_len, aw, awb, x, xb, logits, nullptr, loss,
            0, NBLK_N * 8, 0, 0);
        lse_kernel<<<BATCH, 256, 0, stream>>>(logits, y, loss);
    }
}